// Round 15
// baseline (329.226 us; speedup 1.0000x reference)
//
#include <hip/hip_runtime.h>
#include <math.h>

// ---------------- constants ----------------
#define ETOK 4096      // tokens (edges of graph 1)
#define NE2  65536     // edges of second graph y
#define DEF  200       // node feature dim
#define DM   256       // model dim
#define NH   8         // heads
#define DH   32        // head dim
#define DFFN 2048
#define NKS  8         // attention K-split chunks

// scale * log2(e): folds softmax 1/sqrt(32) and exp->exp2 conversion into Q
#define QSCALE_LOG2E 0.25503474f

typedef __attribute__((ext_vector_type(8))) short bfrag8;   // 8 bf16 (4 VGPR)
typedef __attribute__((ext_vector_type(4))) float f32x4;    // MFMA acc
typedef __attribute__((ext_vector_type(4))) short short4v;
typedef __attribute__((ext_vector_type(4))) unsigned int u32x4;

__device__ __forceinline__ unsigned short f2bf(float f) {
  union { float f; unsigned u; } v; v.f = f;
  unsigned u = v.u + 0x7fffu + ((v.u >> 16) & 1u);   // RNE
  return (unsigned short)(u >> 16);
}
__device__ __forceinline__ float bf2f(unsigned short u) {
  union { unsigned u; float f; } v;
  v.u = ((unsigned)u) << 16;
  return v.f;
}
__device__ __forceinline__ unsigned cvt_pk_bf16(float lo, float hi) {
  unsigned r;
  asm("v_cvt_pk_bf16_f32 %0, %1, %2" : "=v"(r) : "v"(lo), "v"(hi));
  return r;
}

// ---------------- reduction helpers ----------------
__device__ __forceinline__ float wave_sum(float v) {
#pragma unroll
  for (int off = 32; off > 0; off >>= 1) v += __shfl_xor(v, off);
  return v;
}
__device__ __forceinline__ float block_sum(float v, float* red) {
  v = wave_sum(v);
  int lane = threadIdx.x & 63, w = threadIdx.x >> 6;
  if (lane == 0) red[w] = v;
  __syncthreads();
  float t = red[0] + red[1] + red[2] + red[3];
  __syncthreads();
  return t;
}

// ---------------- fused: edge distances + stats (blocks<16) and deg count (all) ----------------
__global__ void edge_deg_kernel(const int* __restrict__ ei, const float* __restrict__ pos,
                                float* __restrict__ ef0, float* __restrict__ stats,
                                const int* __restrict__ y, int* __restrict__ deg) {
  __shared__ float red[4];
  int e2 = blockIdx.x * 256 + threadIdx.x;   // grid 256 -> 65536
  atomicAdd(&deg[y[NE2 + e2]], 1);
  if (blockIdx.x < 16) {
    int e = blockIdx.x * 256 + threadIdx.x;
    int r = ei[e] - 1;
    int c = ei[ETOK + e] - 1;
    float dx = pos[c * 3 + 0] - pos[r * 3 + 0];
    float dy = pos[c * 3 + 1] - pos[r * 3 + 1];
    float dz = pos[c * 3 + 2] - pos[r * 3 + 2];
    float d = sqrtf(dx * dx + dy * dy + dz * dz);
    ef0[e] = d;
    float s = block_sum(d, red);
    float s2 = block_sum(d * d, red);
    if (threadIdx.x == 0) {
      atomicAdd(stats + 0, s);
      atomicAdd(stats + 1, s2);
    }
  }
}

// ---------------- stage 2: token build -> bf16, K-padded to 256 ----------------
__global__ void token_build_kernel(const int* __restrict__ x, const int* __restrict__ ei,
                                   const float* __restrict__ emb, const float* __restrict__ fc1_w,
                                   const float* __restrict__ bn4_g, const float* __restrict__ bn4_b,
                                   const float* __restrict__ ef0, const float* __restrict__ stats,
                                   unsigned short* __restrict__ tokbf) {
  int e = blockIdx.x;
  int j = threadIdx.x;  // 256
  float m = stats[0] * (1.0f / 4096.0f);
  float v = stats[1] * (1.0f / 4096.0f) - m * m;
  int xr = x[ei[e] - 1];
  int xc = x[ei[ETOK + e] - 1];
  float dd = ef0[e] - m;
  float val = 0.f;
  if (j < DEF) {
    float w = fc1_w[j];
    float s = w * rsqrtf(v * w * w + 1e-6f) * bn4_g[j];
    val = emb[(size_t)xr * DEF + j] + emb[(size_t)xc * DEF + j] + dd * s + bn4_b[j];
  }
  tokbf[(size_t)e * 256 + j] = f2bf(val);
}

// ---------------- GCN CSR build ----------------
__global__ void scan_kernel(const int* __restrict__ deg, int* __restrict__ off,
                            int* __restrict__ cursor, float* __restrict__ dinv) {
  __shared__ int part[256];
  int t = threadIdx.x;
  int v[16];
  int s = 0;
#pragma unroll
  for (int i = 0; i < 16; ++i) {
    v[i] = deg[t * 16 + i];
    s += v[i];
  }
  part[t] = s;
  __syncthreads();
  if (t == 0) {
    int a = 0;
#pragma unroll 1
    for (int i = 0; i < 256; ++i) {
      int tmp = part[i];
      part[i] = a;
      a += tmp;
    }
    off[4096] = a;
  }
  __syncthreads();
  int a = part[t];
#pragma unroll
  for (int i = 0; i < 16; ++i) {
    off[t * 16 + i] = a;
    cursor[t * 16 + i] = a;
    dinv[t * 16 + i] = rsqrtf((float)(v[i] + 1));
    a += v[i];
  }
}
__global__ void fill_kernel(const int* __restrict__ y, int* __restrict__ cursor,
                            int* __restrict__ srcl) {
  int e = blockIdx.x * 256 + threadIdx.x;
  int s = y[e];
  int d = y[NE2 + e];
  int slot = atomicAdd(&cursor[d], 1);
  srcl[slot] = s;
}

// ---------------- GCN gather ----------------
template <int RES, int ACT>
__global__ __launch_bounds__(256) void gather_kernel(const float* __restrict__ xw,
                                                     const int* __restrict__ off,
                                                     const int* __restrict__ srcl,
                                                     const float* __restrict__ dinv,
                                                     const float* __restrict__ bias,
                                                     const float* __restrict__ resid,
                                                     float* __restrict__ out) {
  __shared__ int slds[256];
  __shared__ float dlds[256];
  const int d = blockIdx.x;
  const int c = threadIdx.x;
  const int b0 = off[d], b1 = off[d + 1];
  const float dd = dinv[d];
  float acc = 0.f;
  for (int base = b0; base < b1; base += 256) {
    int n = min(256, b1 - base);
    __syncthreads();
    if (c < n) {
      int s = srcl[base + c];
      slds[c] = s;
      dlds[c] = dinv[s];
    }
    __syncthreads();
    for (int j = 0; j < n; ++j) {
      int s = slds[j];
      acc = fmaf(xw[(size_t)s * DM + c], dlds[j], acc);
    }
  }
  size_t idx = (size_t)d * DM + c;
  float v = bias[c] + xw[idx] * dd * dd + acc * dd;
  if (RES) v += resid[idx];
  if (ACT) v = v > 0.f ? v : 0.01f * v;
  out[idx] = v;
}

// ---------------- fused weight transpose+convert: all weights in one launch ----------------
struct WEntry {
  const float* src;
  unsigned short* dst;
  int K, N, KP, tilesN, ntiles;
};
struct WPack {
  WEntry e[10];
};
__global__ __launch_bounds__(256) void wtrans_all_kernel(WPack p) {
  __shared__ float tl[32][33];
  int t = blockIdx.x;
  int i = 0;
  while (t >= p.e[i].ntiles) {
    t -= p.e[i].ntiles;
    ++i;
  }
  const WEntry w = p.e[i];
  int nb = (t % w.tilesN) * 32;
  int kb = (t / w.tilesN) * 32;
  int tx = threadIdx.x & 31, ty = threadIdx.x >> 5;  // 32 x 8
#pragma unroll
  for (int r = ty; r < 32; r += 8) {
    int k = kb + r, n = nb + tx;
    tl[r][tx] = (k < w.K && n < w.N) ? w.src[(size_t)k * w.N + n] : 0.f;
  }
  __syncthreads();
#pragma unroll
  for (int r = ty; r < 32; r += 8) {
    int n = nb + r, k = kb + tx;
    if (n < w.N) w.dst[(size_t)n * w.KP + k] = f2bf(tl[tx][r]);
  }
}

// ---------------- bf16 MFMA GEMM: C = act(A @ Bt^T + bias) ----------------
// QS: scale cols < DM by QSCALE_LOG2E. VSPLIT (N==768): cols<512 -> Cout [M][512];
// cols>=512 -> Cout2 = V transposed [(col-512)][M].
template <int BM, int BN, int OUTBF, int ACT, int QS, int VSPLIT>
__global__ __launch_bounds__(256) void mfma_gemm(const unsigned short* __restrict__ A,
                                                 const unsigned short* __restrict__ Bt,
                                                 const float* __restrict__ bias,
                                                 void* __restrict__ Cout, void* __restrict__ Cout2,
                                                 int M, int N, int K) {
  constexpr int BK = 64;
  constexpr int TM = BM / 32, TN = BN / 32;
  constexpr int ACH = BM / 32, BCH = BN / 32;  // 1KB chunks per wave
  __shared__ unsigned short Alds[BM * BK];
  __shared__ unsigned short Blds[BN * BK];
  const int tid = threadIdx.x;
  const int lane = tid & 63, wid = tid >> 6;
  const int g = lane >> 4, q = lane & 15;
  const int wr = wid >> 1, wc = wid & 1;
  const int m0 = blockIdx.y * BM, n0 = blockIdx.x * BN;

  f32x4 acc[TM][TN];
#pragma unroll
  for (int i = 0; i < TM; ++i)
#pragma unroll
    for (int j = 0; j < TN; ++j) acc[i][j] = (f32x4){0.f, 0.f, 0.f, 0.f};

  for (int k0 = 0; k0 < K; k0 += BK) {
    __syncthreads();
#pragma unroll
    for (int c = 0; c < ACH; ++c) {
      int chunk = wid * ACH + c;
      int row = chunk * 8 + (lane >> 3);
      int cb = ((lane & 7) * 16) ^ ((row & 7) << 4);
      const char* gp = (const char*)A + ((size_t)(m0 + row) * K + k0) * 2 + cb;
      __builtin_amdgcn_global_load_lds(
          (const __attribute__((address_space(1))) unsigned int*)gp,
          (__attribute__((address_space(3))) unsigned int*)(Alds + chunk * 512), 16, 0, 0);
    }
#pragma unroll
    for (int c = 0; c < BCH; ++c) {
      int chunk = wid * BCH + c;
      int row = chunk * 8 + (lane >> 3);
      int cb = ((lane & 7) * 16) ^ ((row & 7) << 4);
      const char* gp = (const char*)Bt + ((size_t)(n0 + row) * K + k0) * 2 + cb;
      __builtin_amdgcn_global_load_lds(
          (const __attribute__((address_space(1))) unsigned int*)gp,
          (__attribute__((address_space(3))) unsigned int*)(Blds + chunk * 512), 16, 0, 0);
    }
    __syncthreads();
#pragma unroll
    for (int ks = 0; ks < 2; ++ks) {
      bfrag8 af[TM], bfr[TN];
#pragma unroll
      for (int mi = 0; mi < TM; ++mi) {
        int row = wr * (BM / 2) + mi * 16 + q;
        int cb = (ks * 64 + g * 16) ^ ((row & 7) << 4);
        af[mi] = *(const bfrag8*)((const char*)Alds + row * 128 + cb);
      }
#pragma unroll
      for (int ni = 0; ni < TN; ++ni) {
        int row = wc * (BN / 2) + ni * 16 + q;
        int cb = (ks * 64 + g * 16) ^ ((row & 7) << 4);
        bfr[ni] = *(const bfrag8*)((const char*)Blds + row * 128 + cb);
      }
#pragma unroll
      for (int mi = 0; mi < TM; ++mi)
#pragma unroll
        for (int ni = 0; ni < TN; ++ni)
          acc[mi][ni] = __builtin_amdgcn_mfma_f32_16x16x32_bf16(af[mi], bfr[ni], acc[mi][ni], 0, 0, 0);
    }
  }
#pragma unroll
  for (int mi = 0; mi < TM; ++mi) {
    int row = m0 + wr * (BM / 2) + mi * 16 + g * 4;
#pragma unroll
    for (int ni = 0; ni < TN; ++ni) {
      int col = n0 + wc * (BN / 2) + ni * 16 + q;
      float bv = bias ? bias[col] : 0.f;
      if (VSPLIT && col >= 512) {
        short4v pkv;
#pragma unroll
        for (int r = 0; r < 4; ++r) pkv[r] = (short)f2bf(acc[mi][ni][r] + bv);
        *(short4v*)((unsigned short*)Cout2 + (size_t)(col - 512) * M + row) = pkv;
      } else {
#pragma unroll
        for (int r = 0; r < 4; ++r) {
          float v = acc[mi][ni][r] + bv;
          if (QS && col < DM) v *= QSCALE_LOG2E;
          if (ACT == 1) v = fmaxf(v, 0.f);
          if (OUTBF)
            ((unsigned short*)Cout)[(size_t)(row + r) * (VSPLIT ? 512 : N) + col] = f2bf(v);
          else
            ((float*)Cout)[(size_t)(row + r) * N + col] = v;
        }
      }
    }
  }
}

// ---------------- BatchNorm: coalesced row-blocked accumulation + apply ----------------
template <int LEAKY>
__global__ __launch_bounds__(256) void col_accum_kernel(const float* __restrict__ x,
                                                        float* __restrict__ colm,
                                                        float* __restrict__ colv) {
  int c = threadIdx.x;
  int r0 = blockIdx.x * 16;
  float s = 0.f, s2 = 0.f;
#pragma unroll
  for (int i = 0; i < 16; ++i) {
    float v = x[(size_t)(r0 + i) * DM + c];
    if (LEAKY) v = v > 0.f ? v : 0.01f * v;
    s += v;
    s2 += v * v;
  }
  atomicAdd(&colm[c], s);
  atomicAdd(&colv[c], s2);
}
template <int LEAKY>
__global__ void bn_apply_kernel(const float* __restrict__ x, const float* __restrict__ colm,
                                const float* __restrict__ colv, const float* __restrict__ g,
                                const float* __restrict__ b, float* __restrict__ outf,
                                unsigned short* __restrict__ outb, int C) {
  size_t i = (size_t)blockIdx.x * 256 + threadIdx.x;
  int c = (int)(i % C);
  float mean = colm[c] * (1.0f / 4096.0f);
  float var = colv[c] * (1.0f / 4096.0f) - mean * mean;
  float v0 = x[i];
  if (LEAKY) v0 = v0 > 0.f ? v0 : 0.01f * v0;
  float v = (v0 - mean) * rsqrtf(var + 1e-6f) * g[c] + b[c];
  outf[i] = v;
  if (outb) outb[i] = f2bf(v);
}

// ---------------- MFMA flash attention: 256-q blocks, NKS=8, LDS 14.5 KB ----------------
// qk: [4096][512] bf16 (Q pre-scaled | K). vt: [256=(h*32+d)][4096] bf16.
// Fixed-max exp2 softmax (m == 0); row-sums l via ones-MFMA on the idle matrix pipe.
// Each wave handles 64 queries (4 fragments) sharing each staged K/V tile; P goes
// through a half-size wave-private LDS buffer, one fragment at a time.
// grid (16, 8, NKS) = 1024 blocks = exact fill at 4 blocks/CU.
__global__ __launch_bounds__(256, 4) void attn_mfma_kernel(const unsigned short* __restrict__ qk,
                                                           const unsigned short* __restrict__ vt,
                                                           unsigned short* __restrict__ Opart,
                                                           float* __restrict__ Lpart) {
  const int h = blockIdx.y;
  const int qblk = blockIdx.x * 256;
  const int chunk = blockIdx.z;
  const int tid = threadIdx.x;
  const int wid = tid >> 6, lane = tid & 63;
  const int g = lane >> 4, q = lane & 15;

  __shared__ unsigned short Klds[64][40];    // 5.1 KB
  __shared__ unsigned int Vtw[32][36];       // 4.6 KB, pre-packed key pairs
  __shared__ unsigned short Plds[4][16][40]; // 5.1 KB per-wave P (one qf, 32-key half)

  bfrag8 qfrag[4];
#pragma unroll
  for (int qf = 0; qf < 4; ++qf) {
    const unsigned short* qp =
        qk + (size_t)(qblk + wid * 64 + qf * 16 + q) * 512 + h * DH + g * 8;
    qfrag[qf] = *(const bfrag8*)qp;
  }
  bfrag8 ones;
#pragma unroll
  for (int i = 0; i < 8; ++i) ones[i] = (short)0x3F80;  // bf16 1.0
  const f32x4 zero = {0.f, 0.f, 0.f, 0.f};

  // staging thread mappings
  const int skey = tid >> 2;           // 0..63 (K row)
  const int sdb = (tid & 3) * 8;       // K dim base
  const int sd = tid >> 3;             // 0..31 (V d index)
  const int sk4 = (tid & 7) * 4;       // V key-pair base (8 keys)

  const int kbeg = chunk * (ETOK / NKS);
  const int NT = (ETOK / NKS) / 64;    // 8 tiles

  const unsigned short* kptr = qk + (size_t)(kbeg + skey) * 512 + DM + h * DH + sdb;
  const unsigned short* vptr = vt + (size_t)(h * DH + sd) * ETOK + kbeg + sk4 * 2;

  // prologue: tile 0 into regs
  bfrag8 kreg = *(const bfrag8*)kptr;
  kptr += (size_t)64 * 512;
  u32x4 vreg = *(const u32x4*)vptr;
  vptr += 64;

  f32x4 o[4][2];
  f32x4 ol[4];
#pragma unroll
  for (int qf = 0; qf < 4; ++qf) {
    o[qf][0] = zero;
    o[qf][1] = zero;
    ol[qf] = zero;
  }

  for (int t = 0; t < NT; ++t) {
    // ---- stage tile t from regs into LDS (single buffer) ----
    *(bfrag8*)&Klds[skey][sdb] = kreg;
    *(u32x4*)&Vtw[sd][sk4] = vreg;
    __syncthreads();
    if (t + 1 < NT) {
      kreg = *(const bfrag8*)kptr;
      kptr += (size_t)64 * 512;
      vreg = *(const u32x4*)vptr;
      vptr += 64;
    }

#pragma unroll
    for (int qf = 0; qf < 4; ++qf) {
      // ---- QK^T for all 64 keys (swapped operands): s[tt][r] = S[16tt+4g+r][q] ----
      f32x4 s[4];
      __builtin_amdgcn_s_setprio(1);
#pragma unroll
      for (int tt = 0; tt < 4; ++tt) {
        bfrag8 kf = *(const bfrag8*)&Klds[tt * 16 + q][g * 8];
        s[tt] = __builtin_amdgcn_mfma_f32_16x16x32_bf16(kf, qfrag[qf], zero, 0, 0, 0);
      }
      __builtin_amdgcn_s_setprio(0);

#pragma unroll
      for (int kg = 0; kg < 2; ++kg) {
        // ---- fixed-max softmax: P = exp2(S); stash 32-key half ----
        {
          uint2 w2;
          w2.x = cvt_pk_bf16(__builtin_exp2f(s[2 * kg][0]), __builtin_exp2f(s[2 * kg][1]));
          w2.y = cvt_pk_bf16(__builtin_exp2f(s[2 * kg][2]), __builtin_exp2f(s[2 * kg][3]));
          *(uint2*)&Plds[wid][q][g * 4] = w2;
          w2.x = cvt_pk_bf16(__builtin_exp2f(s[2 * kg + 1][0]), __builtin_exp2f(s[2 * kg + 1][1]));
          w2.y = cvt_pk_bf16(__builtin_exp2f(s[2 * kg + 1][2]), __builtin_exp2f(s[2 * kg + 1][3]));
          *(uint2*)&Plds[wid][q][16 + g * 4] = w2;
        }
        // ---- PV + row-sum via ones-MFMA ----
        __builtin_amdgcn_s_setprio(1);
        {
          bfrag8 pa = *(const bfrag8*)&Plds[wid][q][g * 8];
          bfrag8 vb0 = *(const bfrag8*)&Vtw[q][kg * 16 + g * 4];
          bfrag8 vb1 = *(const bfrag8*)&Vtw[16 + q][kg * 16 + g * 4];
          o[qf][0] = __builtin_amdgcn_mfma_f32_16x16x32_bf16(pa, vb0, o[qf][0], 0, 0, 0);
          o[qf][1] = __builtin_amdgcn_mfma_f32_16x16x32_bf16(pa, vb1, o[qf][1], 0, 0, 0);
          ol[qf] = __builtin_amdgcn_mfma_f32_16x16x32_bf16(pa, ones, ol[qf], 0, 0, 0);
        }
        __builtin_amdgcn_s_setprio(0);
      }
    }
    __syncthreads();   // all waves done reading K/V before next stage overwrites
  }

  // ---- write partials (bf16 O) + row sums: r9-proven store pattern per fragment ----
#pragma unroll
  for (int qf = 0; qf < 4; ++qf) {
#pragma unroll
    for (int r = 0; r < 4; ++r) {
      int row0 = qblk + wid * 64 + qf * 16 + g * 4 + r;
      unsigned short* op = Opart + ((size_t)chunk * ETOK + row0) * DM + h * DH;
      op[q] = f2bf(o[qf][0][r]);
      op[16 + q] = f2bf(o[qf][1][r]);
    }
    if (q == 0) {
#pragma unroll
      for (int r = 0; r < 4; ++r) {
        int row = qblk + wid * 64 + qf * 16 + g * 4 + r;
        Lpart[((size_t)chunk * ETOK + row) * NH + h] = ol[qf][r];
      }
    }
  }
}

// ---------------- attention combine: plain sum of NKS partials ----------------
__global__ __launch_bounds__(256) void attn_combine_kernel(const unsigned short* __restrict__ Opart,
                                                           const float* __restrict__ Lpart,
                                                           unsigned short* __restrict__ out) {
  __shared__ float ls[NKS][NH];
  const int row = blockIdx.x;
  const int c = threadIdx.x;
  if (c < NKS * NH) {
    ls[c >> 3][c & 7] = Lpart[((size_t)(c >> 3) * ETOK + row) * NH + (c & 7)];
  }
  __syncthreads();
  const int h = c >> 5;
  float lstar = 0.f, acc = 0.f;
#pragma unroll
  for (int ch = 0; ch < NKS; ++ch) {
    lstar += ls[ch][h];
    acc += bf2f(Opart[((size_t)ch * ETOK + row) * DM + c]);
  }
  out[(size_t)row * DM + c] = f2bf(acc / lstar);
}

// ---------------- residual + LayerNorm (dual f32/bf16 out) ----------------
__global__ void add_ln_kernel(const float* __restrict__ x, const float* __restrict__ r,
                              float* __restrict__ outf, unsigned short* __restrict__ outb,
                              const float* __restrict__ g, const float* __restrict__ b) {
  __shared__ float red[4];
  int row = blockIdx.x, t = threadIdx.x;
  size_t idx = (size_t)row * DM + t;
  float v = x[idx] + r[idx];
  float mean = block_sum(v, red) * (1.0f / 256.0f);
  float dv = v - mean;
  float var = block_sum(dv * dv, red) * (1.0f / 256.0f);
  float o = dv * rsqrtf(var + 1e-5f) * g[t] + b[t];
  outf[idx] = o;
  outb[idx] = f2bf(o);
}

// ---------------- output heads with fused leaky + BN ----------------
__global__ void head_kernel(const float* __restrict__ h, const float* __restrict__ colm,
                            const float* __restrict__ colv, const float* __restrict__ bng,
                            const float* __restrict__ bnb, const float* __restrict__ fc3w,
                            const float* __restrict__ fc3b, const float* __restrict__ fc4w,
                            const float* __restrict__ fc4b, float* __restrict__ out) {
  int wave = threadIdx.x >> 6, lane = threadIdx.x & 63;
  int tok = blockIdx.x * 4 + wave;
  const float* hr = h + (size_t)tok * DM;
  float hv[4];
#pragma unroll
  for (int i = 0; i < 4; ++i) {
    int col = lane * 4 + i;
    float v = hr[col];
    v = v > 0.f ? v : 0.01f * v;
    float mean = colm[col] * (1.0f / 4096.0f);
    float var = colv[col] * (1.0f / 4096.0f) - mean * mean;
    hv[i] = (v - mean) * rsqrtf(var + 1e-6f) * bng[col] + bnb[col];
  }
  float acc = 0.f;
#pragma unroll
  for (int i = 0; i < 4; ++i) acc += hv[i] * fc3w[lane * 4 + i];
  acc = wave_sum(acc);
  if (lane == 0) out[tok] = acc + fc3b[0];
#pragma unroll
  for (int j = 0; j < 9; ++j) {
    float a = 0.f;
#pragma unroll
    for (int i = 0; i < 4; ++i) a += hv[i] * fc4w[(lane * 4 + i) * 9 + j];
    a = wave_sum(a);
    if (lane == 0) out[ETOK + (size_t)tok * 9 + j] = a + fc4b[j];
  }
}

// ---------------- launch ----------------
extern "C" void kernel_launch(void* const* d_in, const int* in_sizes, int n_in,
                              void* d_out, int out_size, void* d_ws, size_t ws_size,
                              hipStream_t stream) {
  const int* x = (const int*)d_in[0];
  const int* edge_index = (const int*)d_in[1];
  const float* pos = (const float*)d_in[2];
  const int* y = (const int*)d_in[3];
  const float* emb = (const float*)d_in[4];
  const float* fc1_w = (const float*)d_in[5];
  // d_in[6] = fc1_b cancels inside the batch norm exactly
  const float* bn4_g = (const float*)d_in[7];
  const float* bn4_b = (const float*)d_in[8];
  const float* conv1_w = (const float*)d_in[9];
  const float* conv1_b = (const float*)d_in[10];
  const float* conv2_w = (const float*)d_in[11];
  const float* conv2_b = (const float*)d_in[12];
  const float* bn1_g = (const float*)d_in[13];
  const float* bn1_b = (const float*)d_in[14];
  const float* bn2_g = (const float*)d_in[15];
  const float* bn2_b = (const float*)d_in[16];
  const float* bn3_g = (const float*)d_in[17];
  const float* bn3_b = (const float*)d_in[18];
  const float* ipw = (const float*)d_in[19];
  const float* ipb = (const float*)d_in[20];
  const float* opw = (const float*)d_in[21];
  const float* opb = (const float*)d_in[22];
  const float* ln1_g = (const float*)d_in[23];
  const float* ln1_b = (const float*)d_in[24];
  const float* ln2_g = (const float*)d_in[25];
  const float* ln2_b = (const float*)d_in[26];
  const float* ff1w = (const float*)d_in[27];
  const float* ff1b = (const float*)d_in[28];
  const float* ff2w = (const float*)d_in[29];
  const float* ff2b = (const float*)d_in[30];
  const float* fc3w = (const float*)d_in[31];
  const float* fc3b = (const float*)d_in[32];
  const float* fc4w = (const float*)d_in[33];
  const float* fc4b = (const float*)d_in[34];
  float* outp = (float*)d_out;

  // ---- workspace layout ----
  char* wsp = (char*)d_ws;
  auto alloc = [&](size_t bytes) {
    void* p = (void*)wsp;
    wsp += (bytes + 255) & ~(size_t)255;
    return p;
  };
  unsigned short* big_bf = (unsigned short*)alloc((size_t)ETOK * DFFN * 2);  // ff-mid
  unsigned short* qk_bf = (unsigned short*)alloc((size_t)ETOK * 512 * 2);    // Q|K
  unsigned short* vt_bf = (unsigned short*)alloc((size_t)DM * ETOK * 2);     // V^T [h*32+d][4096]
  unsigned short* attno = (unsigned short*)alloc((size_t)ETOK * DM * 2);
  unsigned short* h_bf = (unsigned short*)alloc((size_t)ETOK * DM * 2);
  unsigned short* tok_bf = (unsigned short*)alloc((size_t)ETOK * 256 * 2);
  float* hf = (float*)alloc((size_t)ETOK * DM * 4);
  float* t1 = (float*)alloc((size_t)ETOK * DM * 4);
  float* t2 = (float*)alloc((size_t)ETOK * DM * 4);
  unsigned short* Opart = (unsigned short*)alloc((size_t)NKS * ETOK * DM * 2);
  float* Lpart = (float*)alloc((size_t)NKS * ETOK * NH * 4);
  unsigned short* c1wt = (unsigned short*)alloc(256 * 256 * 2);
  unsigned short* c2wt = (unsigned short*)alloc(256 * 256 * 2);
  unsigned short* ipwt = (unsigned short*)alloc((size_t)2 * 768 * 256 * 2);
  unsigned short* opwt = (unsigned short*)alloc((size_t)2 * 256 * 256 * 2);
  unsigned short* f1wt = (unsigned short*)alloc((size_t)2 * 2048 * 256 * 2);
  unsigned short* f2wt = (unsigned short*)alloc((size_t)2 * 256 * 2048 * 2);
  float* ef0 = (float*)alloc(ETOK * 4);
  float* dinv = (float*)alloc(ETOK * 4);
  int* off = (int*)alloc((ETOK + 1) * 4);
  int* cursor = (int*)alloc(ETOK * 4);
  int* srcl = (int*)alloc(NE2 * 4);
  // zero-initialized region: stats + 3x colm + 3x colv + deg (single memset)
  char* z0 = wsp;
  float* stats = (float*)alloc(8 * 4);
  float* colm = (float*)alloc(3 * DM * 4);
  float* colv = (float*)alloc(3 * DM * 4);
  int* deg = (int*)alloc(ETOK * 4);
  size_t zlen = (char*)wsp - z0;

  hipMemsetAsync(z0, 0, zlen, stream);

  // ---- fused weight transposes (f32 [K][N] -> bf16 [N][KP]) ----
  WPack wp;
  int ntot = 0;
  auto went = [&](int i, const float* src, unsigned short* dst, int K, int N, int KP) {
    wp.e[i].src = src;
    wp.e[i].dst = dst;
    wp.e[i].K = K;
    wp.e[i].N = N;
    wp.e[i].KP = KP;
    wp.e[i].tilesN = (N + 31) / 32;
    wp.e[i].ntiles = ((N + 31) / 32) * (KP / 32);
    ntot += wp.e[i].ntiles;
  };
  went(0, conv1_w, c1wt, 200, 256, 256);
  went(1, conv2_w, c2wt, 256, 256, 256);
  went(2, ipw, ipwt, 256, 768, 256);
  went(3, ipw + (size_t)256 * 768, ipwt + (size_t)768 * 256, 256, 768, 256);
  went(4, opw, opwt, 256, 256, 256);
  went(5, opw + (size_t)256 * 256, opwt + (size_t)256 * 256, 256, 256, 256);
  went(6, ff1w, f1wt, 256, 2048, 256);
  went(7, ff1w + (size_t)256 * 2048, f1wt + (size_t)2048 * 256, 256, 2048, 256);
  went(8, ff2w, f2wt, 2048, 256, 2048);
  went(9, ff2w + (size_t)2048 * 256, f2wt + (size_t)256 * 2048, 2048, 256, 2048);
  wtrans_all_kernel<<<ntot, 256, 0, stream>>>(wp);

  edge_deg_kernel<<<NE2 / 256, 256, 0, stream>>>(edge_index, pos, ef0, stats, y, deg);
  scan_kernel<<<1, 256, 0, stream>>>(deg, off, cursor, dinv);
  fill_kernel<<<NE2 / 256, 256, 0, stream>>>(y, cursor, srcl);
  token_build_kernel<<<ETOK, 256, 0, stream>>>(x, edge_index, emb, fc1_w, bn4_g, bn4_b, ef0,
                                               stats, tok_bf);

  // ---- GCN conv1: 200(pad 256) -> 256 ----
  mfma_gemm<64, 32, 0, 0, 0, 0><<<dim3(8, 64), 256, 0, stream>>>(tok_bf, c1wt, nullptr, t1,
                                                                 nullptr, ETOK, DM, 256);
  gather_kernel<0, 1><<<ETOK, 256, 0, stream>>>(t1, off, srcl, dinv, conv1_b, nullptr, t2);
  col_accum_kernel<0><<<ETOK / 16, 256, 0, stream>>>(t2, colm, colv);
  bn_apply_kernel<0><<<ETOK * DM / 256, 256, 0, stream>>>(t2, colm, colv, bn1_g, bn1_b, hf, h_bf, DM);

  // ---- GCN conv2: 256 -> 256, residual ----
  mfma_gemm<64, 32, 0, 0, 0, 0><<<dim3(8, 64), 256, 0, stream>>>(h_bf, c2wt, nullptr, t1,
                                                                 nullptr, ETOK, DM, 256);
  gather_kernel<1, 1><<<ETOK, 256, 0, stream>>>(t1, off, srcl, dinv, conv2_b, hf, t2);
  col_accum_kernel<0><<<ETOK / 16, 256, 0, stream>>>(t2, colm + DM, colv + DM);
  bn_apply_kernel<0><<<ETOK * DM / 256, 256, 0, stream>>>(t2, colm + DM, colv + DM, bn2_g, bn2_b,
                                                          hf, h_bf, DM);

  // ---- transformer layers ----
  for (int i = 0; i < 2; ++i) {
    mfma_gemm<64, 32, 1, 0, 1, 1><<<dim3(24, 64), 256, 0, stream>>>(
        h_bf, ipwt + (size_t)i * 768 * 256, ipb + (size_t)i * 768, qk_bf, vt_bf, ETOK, 768, 256);
    attn_mfma_kernel<<<dim3(ETOK / 256, NH, NKS), 256, 0, stream>>>(qk_bf, vt_bf, Opart, Lpart);
    attn_combine_kernel<<<ETOK, 256, 0, stream>>>(Opart, Lpart, attno);
    mfma_gemm<64, 32, 0, 0, 0, 0><<<dim3(8, 64), 256, 0, stream>>>(
        attno, opwt + (size_t)i * 256 * 256, opb + (size_t)i * DM, t2, nullptr, ETOK, DM, 256);
    add_ln_kernel<<<ETOK, 256, 0, stream>>>(t2, hf, hf, h_bf, ln1_g + (size_t)i * DM,
                                            ln1_b + (size_t)i * DM);
    mfma_gemm<64, 64, 1, 1, 0, 0><<<dim3(32, 64), 256, 0, stream>>>(
        h_bf, f1wt + (size_t)i * 2048 * 256, ff1b + (size_t)i * DFFN, big_bf, nullptr, ETOK, DFFN, 256);
    mfma_gemm<64, 32, 0, 0, 0, 0><<<dim3(8, 64), 256, 0, stream>>>(
        big_bf, f2wt + (size_t)i * 256 * 2048, ff2b + (size_t)i * DM, t2, nullptr, ETOK, DM, 2048);
    add_ln_kernel<<<ETOK, 256, 0, stream>>>(t2, hf, hf, h_bf, ln2_g + (size_t)i * DM,
                                            ln2_b + (size_t)i * DM);
  }

  // ---- final leaky+BN fused into stats + head ----
  col_accum_kernel<1><<<ETOK / 16, 256, 0, stream>>>(hf, colm + 2 * DM, colv + 2 * DM);
  head_kernel<<<ETOK / 4, 256, 0, stream>>>(hf, colm + 2 * DM, colv + 2 * DM, bn3_g, bn3_b,
                                            fc3w, fc3b, fc4w, fc4b, outp);
}

// Round 16
// 320.966 us; speedup vs baseline: 1.0257x; 1.0257x over previous
//
#include <hip/hip_runtime.h>
#include <math.h>

// ---------------- constants ----------------
#define ETOK 4096      // tokens (edges of graph 1)
#define NE2  65536     // edges of second graph y
#define DEF  200       // node feature dim
#define DM   256       // model dim
#define NH   8         // heads
#define DH   32        // head dim
#define DFFN 2048
#define NKS  8         // attention K-split chunks

// scale * log2(e): folds softmax 1/sqrt(32) and exp->exp2 conversion into Q
#define QSCALE_LOG2E 0.25503474f

typedef __attribute__((ext_vector_type(8))) short bfrag8;   // 8 bf16 (4 VGPR)
typedef __attribute__((ext_vector_type(4))) float f32x4;    // MFMA acc
typedef __attribute__((ext_vector_type(4))) short short4v;
typedef __attribute__((ext_vector_type(4))) unsigned int u32x4;

__device__ __forceinline__ unsigned short f2bf(float f) {
  union { float f; unsigned u; } v; v.f = f;
  unsigned u = v.u + 0x7fffu + ((v.u >> 16) & 1u);   // RNE
  return (unsigned short)(u >> 16);
}
__device__ __forceinline__ float bf2f(unsigned short u) {
  union { unsigned u; float f; } v;
  v.u = ((unsigned)u) << 16;
  return v.f;
}
__device__ __forceinline__ unsigned cvt_pk_bf16(float lo, float hi) {
  unsigned r;
  asm("v_cvt_pk_bf16_f32 %0, %1, %2" : "=v"(r) : "v"(lo), "v"(hi));
  return r;
}

// ---------------- reduction helpers ----------------
__device__ __forceinline__ float wave_sum(float v) {
#pragma unroll
  for (int off = 32; off > 0; off >>= 1) v += __shfl_xor(v, off);
  return v;
}
__device__ __forceinline__ float block_sum(float v, float* red) {
  v = wave_sum(v);
  int lane = threadIdx.x & 63, w = threadIdx.x >> 6;
  if (lane == 0) red[w] = v;
  __syncthreads();
  float t = red[0] + red[1] + red[2] + red[3];
  __syncthreads();
  return t;
}

// ---------------- fused: edge distances + stats (blocks<16) and deg count (all) ----------------
__global__ void edge_deg_kernel(const int* __restrict__ ei, const float* __restrict__ pos,
                                float* __restrict__ ef0, float* __restrict__ stats,
                                const int* __restrict__ y, int* __restrict__ deg) {
  __shared__ float red[4];
  int e2 = blockIdx.x * 256 + threadIdx.x;   // grid 256 -> 65536
  atomicAdd(&deg[y[NE2 + e2]], 1);
  if (blockIdx.x < 16) {
    int e = blockIdx.x * 256 + threadIdx.x;
    int r = ei[e] - 1;
    int c = ei[ETOK + e] - 1;
    float dx = pos[c * 3 + 0] - pos[r * 3 + 0];
    float dy = pos[c * 3 + 1] - pos[r * 3 + 1];
    float dz = pos[c * 3 + 2] - pos[r * 3 + 2];
    float d = sqrtf(dx * dx + dy * dy + dz * dz);
    ef0[e] = d;
    float s = block_sum(d, red);
    float s2 = block_sum(d * d, red);
    if (threadIdx.x == 0) {
      atomicAdd(stats + 0, s);
      atomicAdd(stats + 1, s2);
    }
  }
}

// ---------------- stage 2: token build -> bf16, K-padded to 256 ----------------
__global__ void token_build_kernel(const int* __restrict__ x, const int* __restrict__ ei,
                                   const float* __restrict__ emb, const float* __restrict__ fc1_w,
                                   const float* __restrict__ bn4_g, const float* __restrict__ bn4_b,
                                   const float* __restrict__ ef0, const float* __restrict__ stats,
                                   unsigned short* __restrict__ tokbf) {
  int e = blockIdx.x;
  int j = threadIdx.x;  // 256
  float m = stats[0] * (1.0f / 4096.0f);
  float v = stats[1] * (1.0f / 4096.0f) - m * m;
  int xr = x[ei[e] - 1];
  int xc = x[ei[ETOK + e] - 1];
  float dd = ef0[e] - m;
  float val = 0.f;
  if (j < DEF) {
    float w = fc1_w[j];
    float s = w * rsqrtf(v * w * w + 1e-6f) * bn4_g[j];
    val = emb[(size_t)xr * DEF + j] + emb[(size_t)xc * DEF + j] + dd * s + bn4_b[j];
  }
  tokbf[(size_t)e * 256 + j] = f2bf(val);
}

// ---------------- GCN CSR build ----------------
__global__ void scan_kernel(const int* __restrict__ deg, int* __restrict__ off,
                            int* __restrict__ cursor, float* __restrict__ dinv) {
  __shared__ int part[256];
  int t = threadIdx.x;
  int v[16];
  int s = 0;
#pragma unroll
  for (int i = 0; i < 16; ++i) {
    v[i] = deg[t * 16 + i];
    s += v[i];
  }
  part[t] = s;
  __syncthreads();
  if (t == 0) {
    int a = 0;
#pragma unroll 1
    for (int i = 0; i < 256; ++i) {
      int tmp = part[i];
      part[i] = a;
      a += tmp;
    }
    off[4096] = a;
  }
  __syncthreads();
  int a = part[t];
#pragma unroll
  for (int i = 0; i < 16; ++i) {
    off[t * 16 + i] = a;
    cursor[t * 16 + i] = a;
    dinv[t * 16 + i] = rsqrtf((float)(v[i] + 1));
    a += v[i];
  }
}
__global__ void fill_kernel(const int* __restrict__ y, int* __restrict__ cursor,
                            int* __restrict__ srcl) {
  int e = blockIdx.x * 256 + threadIdx.x;
  int s = y[e];
  int d = y[NE2 + e];
  int slot = atomicAdd(&cursor[d], 1);
  srcl[slot] = s;
}

// ---------------- GCN gather ----------------
template <int RES, int ACT>
__global__ __launch_bounds__(256) void gather_kernel(const float* __restrict__ xw,
                                                     const int* __restrict__ off,
                                                     const int* __restrict__ srcl,
                                                     const float* __restrict__ dinv,
                                                     const float* __restrict__ bias,
                                                     const float* __restrict__ resid,
                                                     float* __restrict__ out) {
  __shared__ int slds[256];
  __shared__ float dlds[256];
  const int d = blockIdx.x;
  const int c = threadIdx.x;
  const int b0 = off[d], b1 = off[d + 1];
  const float dd = dinv[d];
  float acc = 0.f;
  for (int base = b0; base < b1; base += 256) {
    int n = min(256, b1 - base);
    __syncthreads();
    if (c < n) {
      int s = srcl[base + c];
      slds[c] = s;
      dlds[c] = dinv[s];
    }
    __syncthreads();
    for (int j = 0; j < n; ++j) {
      int s = slds[j];
      acc = fmaf(xw[(size_t)s * DM + c], dlds[j], acc);
    }
  }
  size_t idx = (size_t)d * DM + c;
  float v = bias[c] + xw[idx] * dd * dd + acc * dd;
  if (RES) v += resid[idx];
  if (ACT) v = v > 0.f ? v : 0.01f * v;
  out[idx] = v;
}

// ---------------- fused weight transpose+convert: all weights in one launch ----------------
struct WEntry {
  const float* src;
  unsigned short* dst;
  int K, N, KP, tilesN, ntiles;
};
struct WPack {
  WEntry e[10];
};
__global__ __launch_bounds__(256) void wtrans_all_kernel(WPack p) {
  __shared__ float tl[32][33];
  int t = blockIdx.x;
  int i = 0;
  while (t >= p.e[i].ntiles) {
    t -= p.e[i].ntiles;
    ++i;
  }
  const WEntry w = p.e[i];
  int nb = (t % w.tilesN) * 32;
  int kb = (t / w.tilesN) * 32;
  int tx = threadIdx.x & 31, ty = threadIdx.x >> 5;  // 32 x 8
#pragma unroll
  for (int r = ty; r < 32; r += 8) {
    int k = kb + r, n = nb + tx;
    tl[r][tx] = (k < w.K && n < w.N) ? w.src[(size_t)k * w.N + n] : 0.f;
  }
  __syncthreads();
#pragma unroll
  for (int r = ty; r < 32; r += 8) {
    int n = nb + r, k = kb + tx;
    if (n < w.N) w.dst[(size_t)n * w.KP + k] = f2bf(tl[tx][r]);
  }
}

// ---------------- bf16 MFMA GEMM: C = act(A @ Bt^T + bias) ----------------
// QS: scale cols < DM by QSCALE_LOG2E. VSPLIT (N==768): cols<512 -> Cout [M][512];
// cols>=512 -> Cout2 = V transposed [(col-512)][M].
template <int BM, int BN, int OUTBF, int ACT, int QS, int VSPLIT>
__global__ __launch_bounds__(256) void mfma_gemm(const unsigned short* __restrict__ A,
                                                 const unsigned short* __restrict__ Bt,
                                                 const float* __restrict__ bias,
                                                 void* __restrict__ Cout, void* __restrict__ Cout2,
                                                 int M, int N, int K) {
  constexpr int BK = 64;
  constexpr int TM = BM / 32, TN = BN / 32;
  constexpr int ACH = BM / 32, BCH = BN / 32;  // 1KB chunks per wave
  __shared__ unsigned short Alds[BM * BK];
  __shared__ unsigned short Blds[BN * BK];
  const int tid = threadIdx.x;
  const int lane = tid & 63, wid = tid >> 6;
  const int g = lane >> 4, q = lane & 15;
  const int wr = wid >> 1, wc = wid & 1;
  const int m0 = blockIdx.y * BM, n0 = blockIdx.x * BN;

  f32x4 acc[TM][TN];
#pragma unroll
  for (int i = 0; i < TM; ++i)
#pragma unroll
    for (int j = 0; j < TN; ++j) acc[i][j] = (f32x4){0.f, 0.f, 0.f, 0.f};

  for (int k0 = 0; k0 < K; k0 += BK) {
    __syncthreads();
#pragma unroll
    for (int c = 0; c < ACH; ++c) {
      int chunk = wid * ACH + c;
      int row = chunk * 8 + (lane >> 3);
      int cb = ((lane & 7) * 16) ^ ((row & 7) << 4);
      const char* gp = (const char*)A + ((size_t)(m0 + row) * K + k0) * 2 + cb;
      __builtin_amdgcn_global_load_lds(
          (const __attribute__((address_space(1))) unsigned int*)gp,
          (__attribute__((address_space(3))) unsigned int*)(Alds + chunk * 512), 16, 0, 0);
    }
#pragma unroll
    for (int c = 0; c < BCH; ++c) {
      int chunk = wid * BCH + c;
      int row = chunk * 8 + (lane >> 3);
      int cb = ((lane & 7) * 16) ^ ((row & 7) << 4);
      const char* gp = (const char*)Bt + ((size_t)(n0 + row) * K + k0) * 2 + cb;
      __builtin_amdgcn_global_load_lds(
          (const __attribute__((address_space(1))) unsigned int*)gp,
          (__attribute__((address_space(3))) unsigned int*)(Blds + chunk * 512), 16, 0, 0);
    }
    __syncthreads();
#pragma unroll
    for (int ks = 0; ks < 2; ++ks) {
      bfrag8 af[TM], bfr[TN];
#pragma unroll
      for (int mi = 0; mi < TM; ++mi) {
        int row = wr * (BM / 2) + mi * 16 + q;
        int cb = (ks * 64 + g * 16) ^ ((row & 7) << 4);
        af[mi] = *(const bfrag8*)((const char*)Alds + row * 128 + cb);
      }
#pragma unroll
      for (int ni = 0; ni < TN; ++ni) {
        int row = wc * (BN / 2) + ni * 16 + q;
        int cb = (ks * 64 + g * 16) ^ ((row & 7) << 4);
        bfr[ni] = *(const bfrag8*)((const char*)Blds + row * 128 + cb);
      }
#pragma unroll
      for (int mi = 0; mi < TM; ++mi)
#pragma unroll
        for (int ni = 0; ni < TN; ++ni)
          acc[mi][ni] = __builtin_amdgcn_mfma_f32_16x16x32_bf16(af[mi], bfr[ni], acc[mi][ni], 0, 0, 0);
    }
  }
#pragma unroll
  for (int mi = 0; mi < TM; ++mi) {
    int row = m0 + wr * (BM / 2) + mi * 16 + g * 4;
#pragma unroll
    for (int ni = 0; ni < TN; ++ni) {
      int col = n0 + wc * (BN / 2) + ni * 16 + q;
      float bv = bias ? bias[col] : 0.f;
      if (VSPLIT && col >= 512) {
        short4v pkv;
#pragma unroll
        for (int r = 0; r < 4; ++r) pkv[r] = (short)f2bf(acc[mi][ni][r] + bv);
        *(short4v*)((unsigned short*)Cout2 + (size_t)(col - 512) * M + row) = pkv;
      } else {
#pragma unroll
        for (int r = 0; r < 4; ++r) {
          float v = acc[mi][ni][r] + bv;
          if (QS && col < DM) v *= QSCALE_LOG2E;
          if (ACT == 1) v = fmaxf(v, 0.f);
          if (OUTBF)
            ((unsigned short*)Cout)[(size_t)(row + r) * (VSPLIT ? 512 : N) + col] = f2bf(v);
          else
            ((float*)Cout)[(size_t)(row + r) * N + col] = v;
        }
      }
    }
  }
}

// ---------------- BatchNorm: coalesced row-blocked accumulation + apply ----------------
template <int LEAKY>
__global__ __launch_bounds__(256) void col_accum_kernel(const float* __restrict__ x,
                                                        float* __restrict__ colm,
                                                        float* __restrict__ colv) {
  int c = threadIdx.x;
  int r0 = blockIdx.x * 16;
  float s = 0.f, s2 = 0.f;
#pragma unroll
  for (int i = 0; i < 16; ++i) {
    float v = x[(size_t)(r0 + i) * DM + c];
    if (LEAKY) v = v > 0.f ? v : 0.01f * v;
    s += v;
    s2 += v * v;
  }
  atomicAdd(&colm[c], s);
  atomicAdd(&colv[c], s2);
}
template <int LEAKY>
__global__ void bn_apply_kernel(const float* __restrict__ x, const float* __restrict__ colm,
                                const float* __restrict__ colv, const float* __restrict__ g,
                                const float* __restrict__ b, float* __restrict__ outf,
                                unsigned short* __restrict__ outb, int C) {
  size_t i = (size_t)blockIdx.x * 256 + threadIdx.x;
  int c = (int)(i % C);
  float mean = colm[c] * (1.0f / 4096.0f);
  float var = colv[c] * (1.0f / 4096.0f) - mean * mean;
  float v0 = x[i];
  if (LEAKY) v0 = v0 > 0.f ? v0 : 0.01f * v0;
  float v = (v0 - mean) * rsqrtf(var + 1e-6f) * g[c] + b[c];
  outf[i] = v;
  if (outb) outb[i] = f2bf(v);
}

// ---------------- MFMA flash attention: 128-q blocks, NKS=8, single-buf LDS < 20KB ----------------
// qk: [4096][512] bf16 (Q pre-scaled | K). vt: [256=(h*32+d)][4096] bf16.
// Fixed-max exp2 softmax (m == 0); row-sums l via ones-MFMA on the idle matrix pipe.
// grid (32, 8, NKS), 256 threads = 4 waves x 32 q. LDS 19.5 KB.
__global__ __launch_bounds__(256, 6) void attn_mfma_kernel(const unsigned short* __restrict__ qk,
                                                           const unsigned short* __restrict__ vt,
                                                           unsigned short* __restrict__ Opart,
                                                           float* __restrict__ Lpart) {
  const int h = blockIdx.y;
  const int qblk = blockIdx.x * 128;
  const int chunk = blockIdx.z;
  const int tid = threadIdx.x;
  const int wid = tid >> 6, lane = tid & 63;
  const int g = lane >> 4, q = lane & 15;

  __shared__ unsigned short Klds[64][40];    // 5.1 KB, single-buffered
  __shared__ unsigned int Vtw[32][36];       // 4.6 KB, pre-packed key pairs
  __shared__ unsigned short Plds[4][32][40]; // 10.2 KB per-wave P (32-key half)

  bfrag8 qfrag0, qfrag1;
  {
    const unsigned short* qp = qk + (size_t)(qblk + wid * 32 + q) * 512 + h * DH + g * 8;
    qfrag0 = *(const bfrag8*)qp;
    qfrag1 = *(const bfrag8*)(qp + 16 * 512);
  }
  bfrag8 ones;
#pragma unroll
  for (int i = 0; i < 8; ++i) ones[i] = (short)0x3F80;  // bf16 1.0
  const f32x4 zero = {0.f, 0.f, 0.f, 0.f};

  // staging thread mappings
  const int skey = tid >> 2;           // 0..63 (K row)
  const int sdb = (tid & 3) * 8;       // K dim base
  const int sd = tid >> 3;             // 0..31 (V d index)
  const int sk4 = (tid & 7) * 4;       // V key-pair base (8 keys)

  const int kbeg = chunk * (ETOK / NKS);
  const int NT = (ETOK / NKS) / 64;    // 8 tiles

  const unsigned short* kptr = qk + (size_t)(kbeg + skey) * 512 + DM + h * DH + sdb;
  const unsigned short* vptr = vt + (size_t)(h * DH + sd) * ETOK + kbeg + sk4 * 2;

  // prologue: tile 0 into regs
  bfrag8 kreg = *(const bfrag8*)kptr;
  kptr += (size_t)64 * 512;
  u32x4 vreg = *(const u32x4*)vptr;
  vptr += 64;

  f32x4 o00 = zero, o01 = zero, o10 = zero, o11 = zero;
  f32x4 ol0 = zero, ol1 = zero;   // row sums (all 4 cols equal)

  for (int t = 0; t < NT; ++t) {
    // ---- stage tile t from regs into LDS (single buffer) ----
    *(bfrag8*)&Klds[skey][sdb] = kreg;
    *(u32x4*)&Vtw[sd][sk4] = vreg;
    __syncthreads();
    if (t + 1 < NT) {
      kreg = *(const bfrag8*)kptr;
      kptr += (size_t)64 * 512;
      vreg = *(const u32x4*)vptr;
      vptr += 64;
    }

#pragma unroll
    for (int kg = 0; kg < 2; ++kg) {
      // ---- QK^T for this 32-key half (swapped operands) ----
      f32x4 s0a, s0b, s1a, s1b;
      __builtin_amdgcn_s_setprio(1);
      {
        bfrag8 kfa = *(const bfrag8*)&Klds[(2 * kg) * 16 + q][g * 8];
        bfrag8 kfb = *(const bfrag8*)&Klds[(2 * kg + 1) * 16 + q][g * 8];
        s0a = __builtin_amdgcn_mfma_f32_16x16x32_bf16(kfa, qfrag0, zero, 0, 0, 0);
        s1a = __builtin_amdgcn_mfma_f32_16x16x32_bf16(kfa, qfrag1, zero, 0, 0, 0);
        s0b = __builtin_amdgcn_mfma_f32_16x16x32_bf16(kfb, qfrag0, zero, 0, 0, 0);
        s1b = __builtin_amdgcn_mfma_f32_16x16x32_bf16(kfb, qfrag1, zero, 0, 0, 0);
      }
      __builtin_amdgcn_s_setprio(0);

      // ---- fixed-max softmax: P = exp2(S); stash to per-wave half-P ----
      {
        uint2 w2;
        w2.x = cvt_pk_bf16(__builtin_exp2f(s0a[0]), __builtin_exp2f(s0a[1]));
        w2.y = cvt_pk_bf16(__builtin_exp2f(s0a[2]), __builtin_exp2f(s0a[3]));
        *(uint2*)&Plds[wid][q][g * 4] = w2;
        w2.x = cvt_pk_bf16(__builtin_exp2f(s0b[0]), __builtin_exp2f(s0b[1]));
        w2.y = cvt_pk_bf16(__builtin_exp2f(s0b[2]), __builtin_exp2f(s0b[3]));
        *(uint2*)&Plds[wid][q][16 + g * 4] = w2;
        w2.x = cvt_pk_bf16(__builtin_exp2f(s1a[0]), __builtin_exp2f(s1a[1]));
        w2.y = cvt_pk_bf16(__builtin_exp2f(s1a[2]), __builtin_exp2f(s1a[3]));
        *(uint2*)&Plds[wid][16 + q][g * 4] = w2;
        w2.x = cvt_pk_bf16(__builtin_exp2f(s1b[0]), __builtin_exp2f(s1b[1]));
        w2.y = cvt_pk_bf16(__builtin_exp2f(s1b[2]), __builtin_exp2f(s1b[3]));
        *(uint2*)&Plds[wid][16 + q][16 + g * 4] = w2;
      }

      // ---- PV + row-sum via ones-MFMA ----
      __builtin_amdgcn_s_setprio(1);
      {
        bfrag8 pa0 = *(const bfrag8*)&Plds[wid][q][g * 8];
        bfrag8 pa1 = *(const bfrag8*)&Plds[wid][16 + q][g * 8];
        bfrag8 vb0 = *(const bfrag8*)&Vtw[q][kg * 16 + g * 4];
        bfrag8 vb1 = *(const bfrag8*)&Vtw[16 + q][kg * 16 + g * 4];
        o00 = __builtin_amdgcn_mfma_f32_16x16x32_bf16(pa0, vb0, o00, 0, 0, 0);
        o01 = __builtin_amdgcn_mfma_f32_16x16x32_bf16(pa0, vb1, o01, 0, 0, 0);
        o10 = __builtin_amdgcn_mfma_f32_16x16x32_bf16(pa1, vb0, o10, 0, 0, 0);
        o11 = __builtin_amdgcn_mfma_f32_16x16x32_bf16(pa1, vb1, o11, 0, 0, 0);
        ol0 = __builtin_amdgcn_mfma_f32_16x16x32_bf16(pa0, ones, ol0, 0, 0, 0);
        ol1 = __builtin_amdgcn_mfma_f32_16x16x32_bf16(pa1, ones, ol1, 0, 0, 0);
      }
      __builtin_amdgcn_s_setprio(0);
    }
    __syncthreads();   // all waves done reading K/V before next stage overwrites
  }

  // ---- write partials (bf16 O) + row sums ----
#pragma unroll
  for (int r = 0; r < 4; ++r) {
    int row0 = qblk + wid * 32 + g * 4 + r;
    unsigned short* op0 = Opart + ((size_t)chunk * ETOK + row0) * DM + h * DH;
    op0[q] = f2bf(o00[r]);
    op0[16 + q] = f2bf(o01[r]);
    unsigned short* op1 = op0 + (size_t)16 * DM;
    op1[q] = f2bf(o10[r]);
    op1[16 + q] = f2bf(o11[r]);
  }
  if (q == 0) {
#pragma unroll
    for (int r = 0; r < 4; ++r) {
      int row = qblk + wid * 32 + g * 4 + r;
      Lpart[((size_t)chunk * ETOK + row) * NH + h] = ol0[r];
      Lpart[((size_t)chunk * ETOK + row + 16) * NH + h] = ol1[r];
    }
  }
}

// ---------------- attention combine: plain sum of NKS partials ----------------
__global__ __launch_bounds__(256) void attn_combine_kernel(const unsigned short* __restrict__ Opart,
                                                           const float* __restrict__ Lpart,
                                                           unsigned short* __restrict__ out) {
  __shared__ float ls[NKS][NH];
  const int row = blockIdx.x;
  const int c = threadIdx.x;
  if (c < NKS * NH) {
    ls[c >> 3][c & 7] = Lpart[((size_t)(c >> 3) * ETOK + row) * NH + (c & 7)];
  }
  __syncthreads();
  const int h = c >> 5;
  float lstar = 0.f, acc = 0.f;
#pragma unroll
  for (int ch = 0; ch < NKS; ++ch) {
    lstar += ls[ch][h];
    acc += bf2f(Opart[((size_t)ch * ETOK + row) * DM + c]);
  }
  out[(size_t)row * DM + c] = f2bf(acc / lstar);
}

// ---------------- residual + LayerNorm (dual f32/bf16 out) ----------------
__global__ void add_ln_kernel(const float* __restrict__ x, const float* __restrict__ r,
                              float* __restrict__ outf, unsigned short* __restrict__ outb,
                              const float* __restrict__ g, const float* __restrict__ b) {
  __shared__ float red[4];
  int row = blockIdx.x, t = threadIdx.x;
  size_t idx = (size_t)row * DM + t;
  float v = x[idx] + r[idx];
  float mean = block_sum(v, red) * (1.0f / 256.0f);
  float dv = v - mean;
  float var = block_sum(dv * dv, red) * (1.0f / 256.0f);
  float o = dv * rsqrtf(var + 1e-5f) * g[t] + b[t];
  outf[idx] = o;
  outb[idx] = f2bf(o);
}

// ---------------- output heads with fused leaky + BN ----------------
__global__ void head_kernel(const float* __restrict__ h, const float* __restrict__ colm,
                            const float* __restrict__ colv, const float* __restrict__ bng,
                            const float* __restrict__ bnb, const float* __restrict__ fc3w,
                            const float* __restrict__ fc3b, const float* __restrict__ fc4w,
                            const float* __restrict__ fc4b, float* __restrict__ out) {
  int wave = threadIdx.x >> 6, lane = threadIdx.x & 63;
  int tok = blockIdx.x * 4 + wave;
  const float* hr = h + (size_t)tok * DM;
  float hv[4];
#pragma unroll
  for (int i = 0; i < 4; ++i) {
    int col = lane * 4 + i;
    float v = hr[col];
    v = v > 0.f ? v : 0.01f * v;
    float mean = colm[col] * (1.0f / 4096.0f);
    float var = colv[col] * (1.0f / 4096.0f) - mean * mean;
    hv[i] = (v - mean) * rsqrtf(var + 1e-6f) * bng[col] + bnb[col];
  }
  float acc = 0.f;
#pragma unroll
  for (int i = 0; i < 4; ++i) acc += hv[i] * fc3w[lane * 4 + i];
  acc = wave_sum(acc);
  if (lane == 0) out[tok] = acc + fc3b[0];
#pragma unroll
  for (int j = 0; j < 9; ++j) {
    float a = 0.f;
#pragma unroll
    for (int i = 0; i < 4; ++i) a += hv[i] * fc4w[(lane * 4 + i) * 9 + j];
    a = wave_sum(a);
    if (lane == 0) out[ETOK + (size_t)tok * 9 + j] = a + fc4b[j];
  }
}

// ---------------- launch ----------------
extern "C" void kernel_launch(void* const* d_in, const int* in_sizes, int n_in,
                              void* d_out, int out_size, void* d_ws, size_t ws_size,
                              hipStream_t stream) {
  const int* x = (const int*)d_in[0];
  const int* edge_index = (const int*)d_in[1];
  const float* pos = (const float*)d_in[2];
  const int* y = (const int*)d_in[3];
  const float* emb = (const float*)d_in[4];
  const float* fc1_w = (const float*)d_in[5];
  // d_in[6] = fc1_b cancels inside the batch norm exactly
  const float* bn4_g = (const float*)d_in[7];
  const float* bn4_b = (const float*)d_in[8];
  const float* conv1_w = (const float*)d_in[9];
  const float* conv1_b = (const float*)d_in[10];
  const float* conv2_w = (const float*)d_in[11];
  const float* conv2_b = (const float*)d_in[12];
  const float* bn1_g = (const float*)d_in[13];
  const float* bn1_b = (const float*)d_in[14];
  const float* bn2_g = (const float*)d_in[15];
  const float* bn2_b = (const float*)d_in[16];
  const float* bn3_g = (const float*)d_in[17];
  const float* bn3_b = (const float*)d_in[18];
  const float* ipw = (const float*)d_in[19];
  const float* ipb = (const float*)d_in[20];
  const float* opw = (const float*)d_in[21];
  const float* opb = (const float*)d_in[22];
  const float* ln1_g = (const float*)d_in[23];
  const float* ln1_b = (const float*)d_in[24];
  const float* ln2_g = (const float*)d_in[25];
  const float* ln2_b = (const float*)d_in[26];
  const float* ff1w = (const float*)d_in[27];
  const float* ff1b = (const float*)d_in[28];
  const float* ff2w = (const float*)d_in[29];
  const float* ff2b = (const float*)d_in[30];
  const float* fc3w = (const float*)d_in[31];
  const float* fc3b = (const float*)d_in[32];
  const float* fc4w = (const float*)d_in[33];
  const float* fc4b = (const float*)d_in[34];
  float* outp = (float*)d_out;

  // ---- workspace layout ----
  char* wsp = (char*)d_ws;
  auto alloc = [&](size_t bytes) {
    void* p = (void*)wsp;
    wsp += (bytes + 255) & ~(size_t)255;
    return p;
  };
  unsigned short* big_bf = (unsigned short*)alloc((size_t)ETOK * DFFN * 2);  // ff-mid
  unsigned short* qk_bf = (unsigned short*)alloc((size_t)ETOK * 512 * 2);    // Q|K
  unsigned short* vt_bf = (unsigned short*)alloc((size_t)DM * ETOK * 2);     // V^T [h*32+d][4096]
  unsigned short* attno = (unsigned short*)alloc((size_t)ETOK * DM * 2);
  unsigned short* h_bf = (unsigned short*)alloc((size_t)ETOK * DM * 2);
  unsigned short* tok_bf = (unsigned short*)alloc((size_t)ETOK * 256 * 2);
  float* hf = (float*)alloc((size_t)ETOK * DM * 4);
  float* t1 = (float*)alloc((size_t)ETOK * DM * 4);
  float* t2 = (float*)alloc((size_t)ETOK * DM * 4);
  unsigned short* Opart = (unsigned short*)alloc((size_t)NKS * ETOK * DM * 2);
  float* Lpart = (float*)alloc((size_t)NKS * ETOK * NH * 4);
  unsigned short* c1wt = (unsigned short*)alloc(256 * 256 * 2);
  unsigned short* c2wt = (unsigned short*)alloc(256 * 256 * 2);
  unsigned short* ipwt = (unsigned short*)alloc((size_t)2 * 768 * 256 * 2);
  unsigned short* opwt = (unsigned short*)alloc((size_t)2 * 256 * 256 * 2);
  unsigned short* f1wt = (unsigned short*)alloc((size_t)2 * 2048 * 256 * 2);
  unsigned short* f2wt = (unsigned short*)alloc((size_t)2 * 256 * 2048 * 2);
  float* ef0 = (float*)alloc(ETOK * 4);
  float* dinv = (float*)alloc(ETOK * 4);
  int* off = (int*)alloc((ETOK + 1) * 4);
  int* cursor = (int*)alloc(ETOK * 4);
  int* srcl = (int*)alloc(NE2 * 4);
  // zero-initialized region: stats + 3x colm + 3x colv + deg (single memset)
  char* z0 = wsp;
  float* stats = (float*)alloc(8 * 4);
  float* colm = (float*)alloc(3 * DM * 4);
  float* colv = (float*)alloc(3 * DM * 4);
  int* deg = (int*)alloc(ETOK * 4);
  size_t zlen = (char*)wsp - z0;

  hipMemsetAsync(z0, 0, zlen, stream);

  // ---- fused weight transposes (f32 [K][N] -> bf16 [N][KP]) ----
  WPack wp;
  int ntot = 0;
  auto went = [&](int i, const float* src, unsigned short* dst, int K, int N, int KP) {
    wp.e[i].src = src;
    wp.e[i].dst = dst;
    wp.e[i].K = K;
    wp.e[i].N = N;
    wp.e[i].KP = KP;
    wp.e[i].tilesN = (N + 31) / 32;
    wp.e[i].ntiles = ((N + 31) / 32) * (KP / 32);
    ntot += wp.e[i].ntiles;
  };
  went(0, conv1_w, c1wt, 200, 256, 256);
  went(1, conv2_w, c2wt, 256, 256, 256);
  went(2, ipw, ipwt, 256, 768, 256);
  went(3, ipw + (size_t)256 * 768, ipwt + (size_t)768 * 256, 256, 768, 256);
  went(4, opw, opwt, 256, 256, 256);
  went(5, opw + (size_t)256 * 256, opwt + (size_t)256 * 256, 256, 256, 256);
  went(6, ff1w, f1wt, 256, 2048, 256);
  went(7, ff1w + (size_t)256 * 2048, f1wt + (size_t)2048 * 256, 256, 2048, 256);
  went(8, ff2w, f2wt, 2048, 256, 2048);
  went(9, ff2w + (size_t)2048 * 256, f2wt + (size_t)256 * 2048, 2048, 256, 2048);
  wtrans_all_kernel<<<ntot, 256, 0, stream>>>(wp);

  edge_deg_kernel<<<NE2 / 256, 256, 0, stream>>>(edge_index, pos, ef0, stats, y, deg);
  scan_kernel<<<1, 256, 0, stream>>>(deg, off, cursor, dinv);
  fill_kernel<<<NE2 / 256, 256, 0, stream>>>(y, cursor, srcl);
  token_build_kernel<<<ETOK, 256, 0, stream>>>(x, edge_index, emb, fc1_w, bn4_g, bn4_b, ef0,
                                               stats, tok_bf);

  // ---- GCN conv1: 200(pad 256) -> 256 ----
  mfma_gemm<64, 32, 0, 0, 0, 0><<<dim3(8, 64), 256, 0, stream>>>(tok_bf, c1wt, nullptr, t1,
                                                                 nullptr, ETOK, DM, 256);
  gather_kernel<0, 1><<<ETOK, 256, 0, stream>>>(t1, off, srcl, dinv, conv1_b, nullptr, t2);
  col_accum_kernel<0><<<ETOK / 16, 256, 0, stream>>>(t2, colm, colv);
  bn_apply_kernel<0><<<ETOK * DM / 256, 256, 0, stream>>>(t2, colm, colv, bn1_g, bn1_b, hf, h_bf, DM);

  // ---- GCN conv2: 256 -> 256, residual ----
  mfma_gemm<64, 32, 0, 0, 0, 0><<<dim3(8, 64), 256, 0, stream>>>(h_bf, c2wt, nullptr, t1,
                                                                 nullptr, ETOK, DM, 256);
  gather_kernel<1, 1><<<ETOK, 256, 0, stream>>>(t1, off, srcl, dinv, conv2_b, hf, t2);
  col_accum_kernel<0><<<ETOK / 16, 256, 0, stream>>>(t2, colm + DM, colv + DM);
  bn_apply_kernel<0><<<ETOK * DM / 256, 256, 0, stream>>>(t2, colm + DM, colv + DM, bn2_g, bn2_b,
                                                          hf, h_bf, DM);

  // ---- transformer layers ----
  for (int i = 0; i < 2; ++i) {
    mfma_gemm<64, 32, 1, 0, 1, 1><<<dim3(24, 64), 256, 0, stream>>>(
        h_bf, ipwt + (size_t)i * 768 * 256, ipb + (size_t)i * 768, qk_bf, vt_bf, ETOK, 768, 256);
    attn_mfma_kernel<<<dim3(ETOK / 128, NH, NKS), 256, 0, stream>>>(qk_bf, vt_bf, Opart, Lpart);
    attn_combine_kernel<<<ETOK, 256, 0, stream>>>(Opart, Lpart, attno);
    mfma_gemm<64, 32, 0, 0, 0, 0><<<dim3(8, 64), 256, 0, stream>>>(
        attno, opwt + (size_t)i * 256 * 256, opb + (size_t)i * DM, t2, nullptr, ETOK, DM, 256);
    add_ln_kernel<<<ETOK, 256, 0, stream>>>(t2, hf, hf, h_bf, ln1_g + (size_t)i * DM,
                                            ln1_b + (size_t)i * DM);
    mfma_gemm<64, 64, 1, 1, 0, 0><<<dim3(32, 64), 256, 0, stream>>>(
        h_bf, f1wt + (size_t)i * 2048 * 256, ff1b + (size_t)i * DFFN, big_bf, nullptr, ETOK, DFFN, 256);
    mfma_gemm<64, 32, 0, 0, 0, 0><<<dim3(8, 64), 256, 0, stream>>>(
        big_bf, f2wt + (size_t)i * 256 * 2048, ff2b + (size_t)i * DM, t2, nullptr, ETOK, DM, 2048);
    add_ln_kernel<<<ETOK, 256, 0, stream>>>(t2, hf, hf, h_bf, ln2_g + (size_t)i * DM,
                                            ln2_b + (size_t)i * DM);
  }

  // ---- final leaky+BN fused into stats + head ----
  col_accum_kernel<1><<<ETOK / 16, 256, 0, stream>>>(hf, colm + 2 * DM, colv + 2 * DM);
  head_kernel<<<ETOK / 4, 256, 0, stream>>>(hf, colm + 2 * DM, colv + 2 * DM, bn3_g, bn3_b,
                                            fc3w, fc3b, fc4w, fc4b, outp);
}